// Round 9
// baseline (101.344 us; speedup 1.0000x reference)
//
#include <hip/hip_runtime.h>

#define ALPHA 0.3f
#define NT    50
#define B_    16
#define S_    160
#define RR    40
#define Q_    (RR / 4)            // 10 float4 per rel pair
#define NROW  (B_ * S_)           // 2560
#define NPAIR (B_ * S_ * S_)      // 409600
#define NSEG  (NT * NT)           // 2500
#define NREL4 (NPAIR * Q_)        // 4096000 float4 of rel
#define NARC4 (NPAIR / 4)         // 102400 float4 of arc
#define NCOL  (NT * RR + NT)      // 2050 compact floats per C row
#define CW    2052                // padded C row stride (floats), 8208B (16B-aligned)

#define REL_BLOCKS 2000
#define REL_STRIDE (REL_BLOCKS * 256)   // 512000 ; x8 iters = 4096000 = NREL4 exactly
#define ARC_BLOCKS 50
#define ARC_STRIDE (ARC_BLOCKS * 256)   // 12800  ; x8 iters = 102400 = NARC4 exactly

typedef float v4f __attribute__((ext_vector_type(4)));

__global__ void zero_tab(float* __restrict__ tab, int n) {
    int i = blockIdx.x * blockDim.x + threadIdx.x;
    if (i < n) tab[i] = 0.0f;
}

// ---- DIAGNOSTIC: textbook float4 copy of the rel-sized stream ----
__global__ __launch_bounds__(256) void probe_copy(const v4f* __restrict__ src,
                                                  v4f* __restrict__ dst) {
    int t0 = blockIdx.x * 256 + threadIdx.x;
#pragma unroll
    for (int k = 0; k < 8; ++k) {
        int i = t0 + k * (2048 * 256);
        if (i < NREL4) {
            v4f v = src[i];
            __builtin_nontemporal_store(v, dst + i);
        }
    }
}

// ---- per-batch position lists: deterministic counting sort of adds[b][:] ----
__global__ void build_lists(const int* __restrict__ adds,
                            int* __restrict__ colstart,   // [B_][64]
                            int* __restrict__ collist) {  // [B_][S_]
    __shared__ int tags[S_];
    __shared__ int cnt[NT];
    __shared__ int start[NT + 1];
    int b   = blockIdx.x;
    int tid = threadIdx.x;
    if (tid < S_) tags[tid] = adds[b * S_ + tid];
    __syncthreads();
    if (tid < NT) {
        int c = 0;
        for (int i = 0; i < S_; i++) c += (tags[i] == tid);
        cnt[tid] = c;
    }
    __syncthreads();
    if (tid == 0) {
        int s = 0;
        for (int t = 0; t < NT; t++) { start[t] = s; s += cnt[t]; }
        start[NT] = s;
    }
    __syncthreads();
    if (tid <= NT) colstart[b * 64 + tid] = start[tid];
    if (tid < NT) {
        int slot = start[tid];
        for (int i = 0; i < S_; i++)
            if (tags[i] == tid) collist[b * S_ + slot++] = i;
    }
}

// ---- stage 1: stream whole row into LDS, gather-reduce from LDS. NO atomics. ----
template <int TO_C>
__global__ __launch_bounds__(256) void stage1(const float* __restrict__ a_arc,
                                              const float4* __restrict__ a_rel4,
                                              const int* __restrict__ adds,
                                              const int* __restrict__ colstart,
                                              const int* __restrict__ collist,
                                              float* __restrict__ C,
                                              float* __restrict__ tab_arc,
                                              float* __restrict__ tab_rel) {
    __shared__ float4 a_lds[S_ * Q_];     // 1600 float4 = 25600 B (whole rel row)
    __shared__ float4 aarc_lds[S_ / 4];   // 40 float4 (whole arc row)
    __shared__ int    s_start[NT + 1];
    __shared__ int    s_list[S_];
    int row = blockIdx.x;                 // b*S_ + p1
    int b   = row / S_;
    int tid = threadIdx.x;

    for (int i = tid; i <= NT; i += 256) s_start[i] = colstart[b * 64 + i];
    for (int i = tid; i < S_; i += 256)  s_list[i]  = collist[b * S_ + i];

    const float4* arow = a_rel4 + (size_t)row * (S_ * Q_);
#pragma unroll
    for (int k = 0; k < 7; ++k) {         // 7*256 = 1792 >= 1600
        int idx = k * 256 + tid;
        if (idx < S_ * Q_) a_lds[idx] = arow[idx];
    }
    if (tid < S_ / 4)
        aarc_lds[tid] = ((const float4*)(a_arc + (size_t)row * S_))[tid];
    __syncthreads();

    int t1 = TO_C ? 0 : adds[row];

    for (int cell = tid; cell < NT * Q_; cell += 256) {
        int t2 = cell / Q_;
        int q  = cell - t2 * Q_;
        float4 acc = make_float4(0.f, 0.f, 0.f, 0.f);
        int e1 = s_start[t2 + 1];
        for (int e = s_start[t2]; e < e1; ++e) {
            float4 v = a_lds[s_list[e] * Q_ + q];
            acc.x += v.x; acc.y += v.y; acc.z += v.z; acc.w += v.w;
        }
        if (TO_C) {
            ((float4*)(C + (size_t)row * CW))[cell] = acc;
        } else {
            float* dst = tab_rel + (size_t)t1 * (NT * RR) + cell * 4;
            atomicAdd(dst + 0, acc.x); atomicAdd(dst + 1, acc.y);
            atomicAdd(dst + 2, acc.z); atomicAdd(dst + 3, acc.w);
        }
    }
    if (tid < NT) {
        const float* aarcf = (const float*)aarc_lds;
        float acc = 0.f;
        int e1 = s_start[tid + 1];
        for (int e = s_start[tid]; e < e1; ++e) acc += aarcf[s_list[e]];
        if (TO_C) C[(size_t)row * CW + NT * RR + tid] = acc;
        else      atomicAdd(tab_arc + t1 * NT + tid, acc);
    }
}

// ---- stage 2: reduce C rows grouped by t1 via per-batch lists, NO atomics ----
__global__ __launch_bounds__(256) void stage2(const float* __restrict__ C,
                                              const int* __restrict__ colstart,
                                              const int* __restrict__ collist,
                                              float* __restrict__ tab_arc,
                                              float* __restrict__ tab_rel) {
    int t1 = blockIdx.y;
    int c  = blockIdx.x * 256 + threadIdx.x;
    if (c >= NCOL) return;
    float acc = 0.f;
    for (int b = 0; b < B_; b++) {
        int s0 = colstart[b * 64 + t1], s1 = colstart[b * 64 + t1 + 1];
        for (int j = s0; j < s1; j++) {
            int row = b * S_ + collist[b * S_ + j];
            acc += C[(size_t)row * CW + c];
        }
    }
    if (c < NT * RR) tab_rel[t1 * (NT * RR) + c] = acc;
    else             tab_arc[t1 * NT + (c - NT * RR)] = acc;
}

// key*Q_+q for a rel float4 index t
__device__ __forceinline__ int keyq(const int* __restrict__ pos, int t) {
    int pair = t / Q_;
    int q    = t - pair * Q_;
    int b    = pair / (S_ * S_);
    int rem  = pair - b * (S_ * S_);
    int p1   = rem / S_;
    int p2   = rem - p1 * S_;
    return (pos[b * S_ + p1] * NT + pos[b * S_ + p2]) * Q_ + q;
}

// ---- apply v3: v2 + nontemporal stores ----
__global__ __launch_bounds__(256) void apply_v3(const float* __restrict__ s_arc,
                                                const v4f* __restrict__ s_rel4,
                                                const int* __restrict__ pos,
                                                const float* __restrict__ tab_arc,
                                                const v4f* __restrict__ tab_rel4,
                                                float* __restrict__ out_arc,
                                                v4f* __restrict__ out_rel4) {
    int bid = blockIdx.x, tid = threadIdx.x;
    if (bid < REL_BLOCKS) {
        const int t0 = bid * 256 + tid;
#pragma unroll
        for (int half = 0; half < 2; ++half) {
            const int ta = t0 + (half * 4 + 0) * REL_STRIDE;
            const int tb = t0 + (half * 4 + 1) * REL_STRIDE;
            const int tc = t0 + (half * 4 + 2) * REL_STRIDE;
            const int td = t0 + (half * 4 + 3) * REL_STRIDE;
            v4f sv0 = s_rel4[ta];
            v4f sv1 = s_rel4[tb];
            v4f sv2 = s_rel4[tc];
            v4f sv3 = s_rel4[td];
            int k0 = keyq(pos, ta);
            int k1 = keyq(pos, tb);
            int k2 = keyq(pos, tc);
            int k3 = keyq(pos, td);
            v4f tv0 = tab_rel4[k0];
            v4f tv1 = tab_rel4[k1];
            v4f tv2 = tab_rel4[k2];
            v4f tv3 = tab_rel4[k3];
            v4f o0 = sv0 + ALPHA * tv0;
            v4f o1 = sv1 + ALPHA * tv1;
            v4f o2 = sv2 + ALPHA * tv2;
            v4f o3 = sv3 + ALPHA * tv3;
            __builtin_nontemporal_store(o0, out_rel4 + ta);
            __builtin_nontemporal_store(o1, out_rel4 + tb);
            __builtin_nontemporal_store(o2, out_rel4 + tc);
            __builtin_nontemporal_store(o3, out_rel4 + td);
        }
    } else {
        const int j0 = (bid - REL_BLOCKS) * 256 + tid;
#pragma unroll
        for (int k = 0; k < 8; ++k) {
            int j   = j0 + k * ARC_STRIDE;
            int e0  = j * 4;
            int b   = e0 / (S_ * S_);
            int rem = e0 - b * (S_ * S_);
            int p1  = rem / S_;
            int p2  = rem - p1 * S_;          // multiple of 4
            const int* posb = pos + b * S_;
            int base = posb[p1] * NT;
            v4f sv = ((const v4f*)s_arc)[j];
            v4f o;
            o.x = sv.x + ALPHA * tab_arc[base + posb[p2 + 0]];
            o.y = sv.y + ALPHA * tab_arc[base + posb[p2 + 1]];
            o.z = sv.z + ALPHA * tab_arc[base + posb[p2 + 2]];
            o.w = sv.w + ALPHA * tab_arc[base + posb[p2 + 3]];
            __builtin_nontemporal_store(o, ((v4f*)out_arc) + j);
        }
    }
}

extern "C" void kernel_launch(void* const* d_in, const int* in_sizes, int n_in,
                              void* d_out, int out_size, void* d_ws, size_t ws_size,
                              hipStream_t stream) {
    const float*  a_arc = (const float*)d_in[0];
    const float4* a_rel = (const float4*)d_in[1];
    const float*  s_arc = (const float*)d_in[2];
    const v4f*    s_rel = (const v4f*)d_in[3];
    const int*    adds  = (const int*)d_in[4];
    const int*    pos   = (const int*)d_in[5];

    // workspace layout
    float* tab_arc  = (float*)d_ws;                    // NSEG
    float* tab_rel  = tab_arc + NSEG;                  // NSEG*RR
    int*   colstart = (int*)(tab_rel + NSEG * RR);     // B_*64
    int*   collist  = colstart + B_ * 64;              // B_*S_
    float* C        = (float*)(collist + B_ * S_);     // NROW*CW
    C = (float*)(((uintptr_t)C + 15) & ~(uintptr_t)15);
    v4f*   probe_dst = (v4f*)(C + (size_t)NROW * CW);  // NREL4 float4 scratch

    size_t need_lists = (size_t)(NSEG * (RR + 1)) * 4
                      + (size_t)(B_ * 64 + B_ * S_) * 4 + 16;
    size_t need_full  = need_lists + (size_t)NROW * CW * 4;
    size_t need_probe = need_full + (size_t)NREL4 * 16;

    float* out_arc = (float*)d_out;                    // NPAIR
    v4f*   out_rel = (v4f*)(out_arc + NPAIR);          // NREL4

    const int BLK = 256;

    build_lists<<<B_, 192, 0, stream>>>(adds, colstart, collist);

    if (ws_size >= need_full) {
        stage1<1><<<NROW, 256, 0, stream>>>(a_arc, a_rel, adds, colstart, collist,
                                            C, nullptr, nullptr);
        dim3 g2((NCOL + 255) / 256, NT);
        stage2<<<g2, 256, 0, stream>>>(C, colstart, collist, tab_arc, tab_rel);
    } else {
        int n_tab = NSEG * (RR + 1);
        zero_tab<<<(n_tab + BLK - 1) / BLK, BLK, 0, stream>>>(tab_arc, n_tab);
        stage1<0><<<NROW, 256, 0, stream>>>(a_arc, a_rel, adds, colstart, collist,
                                            nullptr, tab_arc, tab_rel);
    }

    // DIAGNOSTIC (one round only): ground-truth stream ceiling for this shape.
    if (ws_size >= need_probe) {
        probe_copy<<<2048, 256, 0, stream>>>(s_rel, probe_dst);
    }

    apply_v3<<<REL_BLOCKS + ARC_BLOCKS, 256, 0, stream>>>(
        s_arc, s_rel, pos, tab_arc, (const v4f*)tab_rel, out_arc, out_rel);
}

// Round 10
// 81.994 us; speedup vs baseline: 1.2360x; 1.2360x over previous
//
#include <hip/hip_runtime.h>

#define ALPHA 0.3f
#define NT    50
#define B_    16
#define S_    160
#define RR    40
#define Q_    (RR / 4)            // 10 float4 per rel pair
#define NROW  (B_ * S_)           // 2560
#define NPAIR (B_ * S_ * S_)      // 409600
#define NSEG  (NT * NT)           // 2500
#define NREL4 (NPAIR * Q_)        // 4096000 float4 of rel
#define NCOL  (NT * RR + NT)      // 2050 compact floats per C row
#define CW    2052                // padded C row stride (floats), 8208B (16B-aligned)

typedef float v4f __attribute__((ext_vector_type(4)));

__global__ void zero_tab(float* __restrict__ tab, int n) {
    int i = blockIdx.x * blockDim.x + threadIdx.x;
    if (i < n) tab[i] = 0.0f;
}

// ---- per-batch position lists: deterministic counting sort of adds[b][:] ----
__global__ void build_lists(const int* __restrict__ adds,
                            int* __restrict__ colstart,   // [B_][64]
                            int* __restrict__ collist) {  // [B_][S_]
    __shared__ int tags[S_];
    __shared__ int cnt[NT];
    __shared__ int start[NT + 1];
    int b   = blockIdx.x;
    int tid = threadIdx.x;
    if (tid < S_) tags[tid] = adds[b * S_ + tid];
    __syncthreads();
    if (tid < NT) {
        int c = 0;
        for (int i = 0; i < S_; i++) c += (tags[i] == tid);
        cnt[tid] = c;
    }
    __syncthreads();
    if (tid == 0) {
        int s = 0;
        for (int t = 0; t < NT; t++) { start[t] = s; s += cnt[t]; }
        start[NT] = s;
    }
    __syncthreads();
    if (tid <= NT) colstart[b * 64 + tid] = start[tid];
    if (tid < NT) {
        int slot = start[tid];
        for (int i = 0; i < S_; i++)
            if (tags[i] == tid) collist[b * S_ + slot++] = i;
    }
}

// ---- stage 1: stream whole row into LDS, gather-reduce from LDS. NO atomics. ----
template <int TO_C>
__global__ __launch_bounds__(256) void stage1(const float* __restrict__ a_arc,
                                              const float4* __restrict__ a_rel4,
                                              const int* __restrict__ adds,
                                              const int* __restrict__ colstart,
                                              const int* __restrict__ collist,
                                              float* __restrict__ C,
                                              float* __restrict__ tab_arc,
                                              float* __restrict__ tab_rel) {
    __shared__ float4 a_lds[S_ * Q_];     // 1600 float4 = 25600 B (whole rel row)
    __shared__ float4 aarc_lds[S_ / 4];   // 40 float4 (whole arc row)
    __shared__ int    s_start[NT + 1];
    __shared__ int    s_list[S_];
    int row = blockIdx.x;                 // b*S_ + p1
    int b   = row / S_;
    int tid = threadIdx.x;

    for (int i = tid; i <= NT; i += 256) s_start[i] = colstart[b * 64 + i];
    for (int i = tid; i < S_; i += 256)  s_list[i]  = collist[b * S_ + i];

    const float4* arow = a_rel4 + (size_t)row * (S_ * Q_);
#pragma unroll
    for (int k = 0; k < 7; ++k) {         // 7*256 = 1792 >= 1600
        int idx = k * 256 + tid;
        if (idx < S_ * Q_) a_lds[idx] = arow[idx];
    }
    if (tid < S_ / 4)
        aarc_lds[tid] = ((const float4*)(a_arc + (size_t)row * S_))[tid];
    __syncthreads();

    int t1 = TO_C ? 0 : adds[row];

    for (int cell = tid; cell < NT * Q_; cell += 256) {
        int t2 = cell / Q_;
        int q  = cell - t2 * Q_;
        float4 acc = make_float4(0.f, 0.f, 0.f, 0.f);
        int e1 = s_start[t2 + 1];
        for (int e = s_start[t2]; e < e1; ++e) {
            float4 v = a_lds[s_list[e] * Q_ + q];
            acc.x += v.x; acc.y += v.y; acc.z += v.z; acc.w += v.w;
        }
        if (TO_C) {
            ((float4*)(C + (size_t)row * CW))[cell] = acc;
        } else {
            float* dst = tab_rel + (size_t)t1 * (NT * RR) + cell * 4;
            atomicAdd(dst + 0, acc.x); atomicAdd(dst + 1, acc.y);
            atomicAdd(dst + 2, acc.z); atomicAdd(dst + 3, acc.w);
        }
    }
    if (tid < NT) {
        const float* aarcf = (const float*)aarc_lds;
        float acc = 0.f;
        int e1 = s_start[tid + 1];
        for (int e = s_start[tid]; e < e1; ++e) acc += aarcf[s_list[e]];
        if (TO_C) C[(size_t)row * CW + NT * RR + tid] = acc;
        else      atomicAdd(tab_arc + t1 * NT + tid, acc);
    }
}

// ---- stage 2: reduce C rows grouped by t1 via per-batch lists, NO atomics ----
__global__ __launch_bounds__(256) void stage2(const float* __restrict__ C,
                                              const int* __restrict__ colstart,
                                              const int* __restrict__ collist,
                                              float* __restrict__ tab_arc,
                                              float* __restrict__ tab_rel) {
    int t1 = blockIdx.y;
    int c  = blockIdx.x * 256 + threadIdx.x;
    if (c >= NCOL) return;
    float acc = 0.f;
    for (int b = 0; b < B_; b++) {
        int s0 = colstart[b * 64 + t1], s1 = colstart[b * 64 + t1 + 1];
        for (int j = s0; j < s1; j++) {
            int row = b * S_ + collist[b * S_ + j];
            acc += C[(size_t)row * CW + c];
        }
    }
    if (c < NT * RR) tab_rel[t1 * (NT * RR) + c] = acc;
    else             tab_arc[t1 * NT + (c - NT * RR)] = acc;
}

// ---- apply v4: LDS-staged table (zero scattered global reads in the hot loop)
//                + nontemporal stores (no L2 write-allocate pollution).
// One block per (b,p1) row: table slice is only 50 rows (t1 fixed by p1).
__global__ __launch_bounds__(256) void apply_v4(const float* __restrict__ s_arc,
                                                const v4f* __restrict__ s_rel4,
                                                const int* __restrict__ pos,
                                                const float* __restrict__ tab_arc,
                                                const v4f* __restrict__ tab_rel4,
                                                float* __restrict__ out_arc,
                                                v4f* __restrict__ out_rel4) {
    __shared__ v4f   s_tab[NT][Q_ + 1];   // pad: 176B stride breaks bank aliasing
    __shared__ float s_tarc[NT];
    __shared__ int   s_pos[S_];
    int row = blockIdx.x;                 // b*S_ + p1
    int b   = row / S_;
    int p1  = row - b * S_;
    int tid = threadIdx.x;

    int base = pos[b * S_ + p1] * NT;     // wave-uniform broadcast load
    for (int cell = tid; cell < NT * Q_; cell += 256) {
        int t2 = cell / Q_;
        int q  = cell - t2 * Q_;
        s_tab[t2][q] = tab_rel4[(base + t2) * Q_ + q];   // coalesced 8 KB
    }
    if (tid < NT) s_tarc[tid] = tab_arc[base + tid];
    if (tid < S_) s_pos[tid] = pos[b * S_ + tid];
    __syncthreads();

    const v4f* srow = s_rel4   + (size_t)row * (S_ * Q_);
    v4f*       orow = out_rel4 + (size_t)row * (S_ * Q_);
#pragma unroll
    for (int k = 0; k < 7; ++k) {         // 7*256 = 1792 >= 1600, compile-time
        int e = k * 256 + tid;
        if (e < S_ * Q_) {
            int p2 = e / Q_;
            int q  = e - p2 * Q_;
            v4f sv = srow[e];             // plain load: keep L3 residency
            v4f tv = s_tab[s_pos[p2]][q];
            __builtin_nontemporal_store(sv + ALPHA * tv, orow + e);
        }
    }
    if (tid < S_) {
        float v = s_arc[(size_t)row * S_ + tid] + ALPHA * s_tarc[s_pos[tid]];
        __builtin_nontemporal_store(v, out_arc + (size_t)row * S_ + tid);
    }
}

extern "C" void kernel_launch(void* const* d_in, const int* in_sizes, int n_in,
                              void* d_out, int out_size, void* d_ws, size_t ws_size,
                              hipStream_t stream) {
    const float*  a_arc = (const float*)d_in[0];
    const float4* a_rel = (const float4*)d_in[1];
    const float*  s_arc = (const float*)d_in[2];
    const v4f*    s_rel = (const v4f*)d_in[3];
    const int*    adds  = (const int*)d_in[4];
    const int*    pos   = (const int*)d_in[5];

    // workspace layout
    float* tab_arc  = (float*)d_ws;                    // NSEG
    float* tab_rel  = tab_arc + NSEG;                  // NSEG*RR
    int*   colstart = (int*)(tab_rel + NSEG * RR);     // B_*64
    int*   collist  = colstart + B_ * 64;              // B_*S_
    float* C        = (float*)(collist + B_ * S_);     // NROW*CW
    C = (float*)(((uintptr_t)C + 15) & ~(uintptr_t)15);

    size_t need_lists = (size_t)(NSEG * (RR + 1)) * 4
                      + (size_t)(B_ * 64 + B_ * S_) * 4 + 16;
    size_t need_full  = need_lists + (size_t)NROW * CW * 4;

    float* out_arc = (float*)d_out;                    // NPAIR
    v4f*   out_rel = (v4f*)(out_arc + NPAIR);          // NREL4

    const int BLK = 256;

    build_lists<<<B_, 192, 0, stream>>>(adds, colstart, collist);

    if (ws_size >= need_full) {
        stage1<1><<<NROW, 256, 0, stream>>>(a_arc, a_rel, adds, colstart, collist,
                                            C, nullptr, nullptr);
        dim3 g2((NCOL + 255) / 256, NT);
        stage2<<<g2, 256, 0, stream>>>(C, colstart, collist, tab_arc, tab_rel);
    } else {
        int n_tab = NSEG * (RR + 1);
        zero_tab<<<(n_tab + BLK - 1) / BLK, BLK, 0, stream>>>(tab_arc, n_tab);
        stage1<0><<<NROW, 256, 0, stream>>>(a_arc, a_rel, adds, colstart, collist,
                                            nullptr, tab_arc, tab_rel);
    }

    apply_v4<<<NROW, 256, 0, stream>>>(s_arc, s_rel, pos, tab_arc,
                                       (const v4f*)tab_rel, out_arc, out_rel);
}